// Round 1
// baseline (346.223 us; speedup 1.0000x reference)
//
#include <hip/hip_runtime.h>

#define N_NODES 50000
#define N_EDGES 1600000
#define N_HEAD 4
#define F_OUT 128
#define CAP 96        // per-node bucket capacity; Poisson(32), P(>96) ~ 5e-14
#define NPS 512       // nodes per super-bucket
#define K1 98         // ceil(50000/512)
#define SCAP 17408    // super capacity: mean 16384 + 8 sigma(128)
#define NPG 32        // nodes per agg block
#define GROUPS 1563   // ceil(50000/32)
#define EPB 4096      // edges per partition block
#define P1_BLOCKS ((N_EDGES + EPB - 1) / EPB)   // 391

// ---------------- K1: per-node scores, packed float4 (h0..h3) per node ----------
__global__ void __launch_bounds__(256) score_kernel(
    const float* __restrict__ x, const float* __restrict__ w,
    const float* __restrict__ a, float4* __restrict__ s_src4,
    float4* __restrict__ s_dst4) {
  int wv = (blockIdx.x * blockDim.x + threadIdx.x) >> 6;
  int lane = threadIdx.x & 63;
  if (wv >= N_NODES) return;
  float xv0 = x[wv * F_OUT + lane];
  float xv1 = x[wv * F_OUT + 64 + lane];
  float ps[N_HEAD], pd[N_HEAD];
#pragma unroll
  for (int h = 0; h < N_HEAD; ++h) {
    float w0 = w[h * F_OUT + lane];
    float w1 = w[h * F_OUT + 64 + lane];
    float as0 = a[h * 2 * F_OUT + lane];
    float as1 = a[h * 2 * F_OUT + 64 + lane];
    float ad0 = a[h * 2 * F_OUT + F_OUT + lane];
    float ad1 = a[h * 2 * F_OUT + F_OUT + 64 + lane];
    ps[h] = xv0 * w0 * as0 + xv1 * w1 * as1;
    pd[h] = xv0 * w0 * ad0 + xv1 * w1 * ad1;
  }
#pragma unroll
  for (int off = 32; off > 0; off >>= 1) {
#pragma unroll
    for (int h = 0; h < N_HEAD; ++h) {
      ps[h] += __shfl_xor(ps[h], off, 64);
      pd[h] += __shfl_xor(pd[h], off, 64);
    }
  }
  if (lane == 0) {
    s_src4[wv] = make_float4(ps[0], ps[1], ps[2], ps[3]);
    s_dst4[wv] = make_float4(pd[0], pd[1], pd[2], pd[3]);
  }
}

// ---------------- K2: block-local counting sort -> coalesced run writes ---------
// Packs (src<<16)|dst (both < 65536). Coarse bucket = src>>9 (=packed>>25).
__global__ void __launch_bounds__(256) partition_kernel(
    const int* __restrict__ src, const int* __restrict__ dst,
    int* __restrict__ gc, unsigned int* __restrict__ region) {
  __shared__ int hist[K1], cur[K1], lstart[K1], gpos[K1];
  __shared__ unsigned int staging[EPB];
  const int tid = threadIdx.x;
  const int base = blockIdx.x * EPB;
  int vc = N_EDGES - base;
  if (vc > EPB) vc = EPB;

  unsigned int pk[EPB / 256];
#pragma unroll
  for (int k = 0; k < EPB / 256; ++k) {
    int i = k * 256 + tid;
    if (i < vc) {
      unsigned int s = (unsigned int)src[base + i];
      unsigned int d = (unsigned int)dst[base + i];
      pk[k] = (s << 16) | d;           // valid packed can never be 0xffffffff
    } else {
      pk[k] = 0xffffffffu;
    }
  }
  if (tid < K1) { hist[tid] = 0; cur[tid] = 0; }
  __syncthreads();
#pragma unroll
  for (int k = 0; k < EPB / 256; ++k)
    if (pk[k] != 0xffffffffu) atomicAdd(&hist[pk[k] >> 25], 1);
  __syncthreads();
  // wave 0: exclusive scan of hist + global reservation
  if (tid < 64) {
    int carry = 0;
    for (int b0 = 0; b0 < K1; b0 += 64) {
      int idx = b0 + tid;
      int h = (idx < K1) ? hist[idx] : 0;
      int v = h;
#pragma unroll
      for (int off = 1; off < 64; off <<= 1) {
        int t = __shfl_up(v, off, 64);
        if (tid >= off) v += t;
      }
      if (idx < K1) {
        lstart[idx] = carry + v - h;
        gpos[idx] = atomicAdd(&gc[idx], h);
      }
      carry += __shfl(v, 63, 64);
    }
  }
  __syncthreads();
  // place into LDS staging, sorted by coarse bucket
#pragma unroll
  for (int k = 0; k < EPB / 256; ++k) {
    if (pk[k] != 0xffffffffu) {
      int b = pk[k] >> 25;
      int pos = lstart[b] + atomicAdd(&cur[b], 1);
      staging[pos] = pk[k];
    }
  }
  __syncthreads();
  // copy out: consecutive lanes -> consecutive global addresses within each run
  for (int i = tid; i < vc; i += 256) {
    unsigned int v = staging[i];
    int b = v >> 25;
    int off = gpos[b] + (i - lstart[b]);
    if (off < SCAP) region[(size_t)b * SCAP + off] = v;
  }
}

// ---------------- K3: fused LDS-bucket + gather/accumulate ----------------------
// One block per 32-node group; scans its super region, LDS-buckets its edges,
// then wave-per-node phase A (weights) / phase B (x-gather + FMA).
__global__ void __launch_bounds__(256) agg_kernel(
    const float* __restrict__ x, const float* __restrict__ w,
    const float4* __restrict__ s_src4, const float4* __restrict__ s_dst4,
    const int* __restrict__ gc, const unsigned int* __restrict__ region,
    float* __restrict__ out) {
  __shared__ int ncnt[NPG];
  __shared__ int nbkt[NPG][CAP];
  __shared__ float4 lds_w[4][CAP];
  const int tid = threadIdx.x;
  const int g = blockIdx.x;
  const int sb = g >> 4;                 // 16 groups per super (512/32)
  int c = gc[sb];
  if (c > SCAP) c = SCAP;
  if (tid < NPG) ncnt[tid] = 0;
  __syncthreads();

  const unsigned int* reg = region + (size_t)sb * SCAP;
  const unsigned int gtag = (unsigned int)g;
  for (int i = tid; i < c; i += 256) {
    unsigned int v = reg[i];
    unsigned int s = v >> 16;
    if ((s >> 5) == gtag) {
      int l = s & 31;
      int p = atomicAdd(&ncnt[l], 1);
      if (p < CAP) nbkt[l][p] = (int)(v & 0xffffu);
    }
  }
  __syncthreads();

  const int ws = tid >> 6, lane = tid & 63;
  const float* xp = x + 2 * lane;

  // node-invariant epilogue weights (hoisted out of the node loop)
  const float2 wl0 = *(const float2*)(w + 0 * F_OUT + 2 * lane);
  const float2 wl1 = *(const float2*)(w + 1 * F_OUT + 2 * lane);
  const float2 wl2 = *(const float2*)(w + 2 * F_OUT + 2 * lane);
  const float2 wl3 = *(const float2*)(w + 3 * F_OUT + 2 * lane);

  for (int l = ws; l < NPG; l += 4) {
    int n = g * NPG + l;
    if (n >= N_NODES) break;
    int m = ncnt[l];
    m = (m < CAP) ? m : CAP;
    float4 ss = s_src4[n];

    // ---- Phase A: weights into wave-private LDS, per-lane partial rowsums ----
    // (cross-lane reduction deferred to the epilogue so phase B's gathers can
    //  issue immediately after the last weight is written)
    float p0 = 0.f, p1 = 0.f, p2 = 0.f, p3 = 0.f;
    for (int j = lane; j < m; j += 64) {
      int d = nbkt[l][j];
      float4 sd = s_dst4[d];
      float sc0 = ss.x + sd.x, sc1 = ss.y + sd.y, sc2 = ss.z + sd.z, sc3 = ss.w + sd.w;
      float e0 = __expf(-fmaxf(sc0, 0.2f * sc0));
      float e1 = __expf(-fmaxf(sc1, 0.2f * sc1));
      float e2 = __expf(-fmaxf(sc2, 0.2f * sc2));
      float e3 = __expf(-fmaxf(sc3, 0.2f * sc3));
      lds_w[ws][j] = make_float4(e0, e1, e2, e3);
      p0 += e0; p1 += e1; p2 += e2; p3 += e3;
    }

    // ---- Phase B: x-gather + FMA, unroll x4 (4 gathers in flight/wave) ----
    float2 a0 = {0.f, 0.f}, a1 = {0.f, 0.f}, a2 = {0.f, 0.f}, a3 = {0.f, 0.f};
    int j = 0;
    for (; j + 3 < m; j += 4) {
      int4 dd = *(const int4*)&nbkt[l][j];        // 16B-aligned b128 LDS read
      float4 w0 = lds_w[ws][j];
      float4 w1 = lds_w[ws][j + 1];
      float4 w2 = lds_w[ws][j + 2];
      float4 w3 = lds_w[ws][j + 3];
      float2 x0 = *(const float2*)(xp + (size_t)dd.x * F_OUT);
      float2 x1 = *(const float2*)(xp + (size_t)dd.y * F_OUT);
      float2 x2 = *(const float2*)(xp + (size_t)dd.z * F_OUT);
      float2 x3 = *(const float2*)(xp + (size_t)dd.w * F_OUT);
      a0.x = fmaf(w0.x, x0.x, a0.x); a0.y = fmaf(w0.x, x0.y, a0.y);
      a1.x = fmaf(w0.y, x0.x, a1.x); a1.y = fmaf(w0.y, x0.y, a1.y);
      a2.x = fmaf(w0.z, x0.x, a2.x); a2.y = fmaf(w0.z, x0.y, a2.y);
      a3.x = fmaf(w0.w, x0.x, a3.x); a3.y = fmaf(w0.w, x0.y, a3.y);
      a0.x = fmaf(w1.x, x1.x, a0.x); a0.y = fmaf(w1.x, x1.y, a0.y);
      a1.x = fmaf(w1.y, x1.x, a1.x); a1.y = fmaf(w1.y, x1.y, a1.y);
      a2.x = fmaf(w1.z, x1.x, a2.x); a2.y = fmaf(w1.z, x1.y, a2.y);
      a3.x = fmaf(w1.w, x1.x, a3.x); a3.y = fmaf(w1.w, x1.y, a3.y);
      a0.x = fmaf(w2.x, x2.x, a0.x); a0.y = fmaf(w2.x, x2.y, a0.y);
      a1.x = fmaf(w2.y, x2.x, a1.x); a1.y = fmaf(w2.y, x2.y, a1.y);
      a2.x = fmaf(w2.z, x2.x, a2.x); a2.y = fmaf(w2.z, x2.y, a2.y);
      a3.x = fmaf(w2.w, x2.x, a3.x); a3.y = fmaf(w2.w, x2.y, a3.y);
      a0.x = fmaf(w3.x, x3.x, a0.x); a0.y = fmaf(w3.x, x3.y, a0.y);
      a1.x = fmaf(w3.y, x3.x, a1.x); a1.y = fmaf(w3.y, x3.y, a1.y);
      a2.x = fmaf(w3.z, x3.x, a2.x); a2.y = fmaf(w3.z, x3.y, a2.y);
      a3.x = fmaf(w3.w, x3.x, a3.x); a3.y = fmaf(w3.w, x3.y, a3.y);
    }
    for (; j < m; ++j) {
      int d0 = nbkt[l][j];
      float4 w0 = lds_w[ws][j];
      float2 x0 = *(const float2*)(xp + (size_t)d0 * F_OUT);
      a0.x = fmaf(w0.x, x0.x, a0.x); a0.y = fmaf(w0.x, x0.y, a0.y);
      a1.x = fmaf(w0.y, x0.x, a1.x); a1.y = fmaf(w0.y, x0.y, a1.y);
      a2.x = fmaf(w0.z, x0.x, a2.x); a2.y = fmaf(w0.z, x0.y, a2.y);
      a3.x = fmaf(w0.w, x0.x, a3.x); a3.y = fmaf(w0.w, x0.y, a3.y);
    }

    // ---- deferred rowsum reduction (independent of phase B accumulators) ----
#pragma unroll
    for (int off = 32; off > 0; off >>= 1) {
      p0 += __shfl_xor(p0, off, 64);
      p1 += __shfl_xor(p1, off, 64);
      p2 += __shfl_xor(p2, off, 64);
      p3 += __shfl_xor(p3, off, 64);
    }

    // ---- epilogue ----
    float r0 = 1.f / p0, r1 = 1.f / p1, r2 = 1.f / p2, r3 = 1.f / p3;

    float2 o;
    o.x = wl0.x * a0.x * r0; o.y = wl0.y * a0.y * r0;
    *(float2*)(out + ((size_t)0 * N_NODES + n) * F_OUT + 2 * lane) = o;
    o.x = wl1.x * a1.x * r1; o.y = wl1.y * a1.y * r1;
    *(float2*)(out + ((size_t)1 * N_NODES + n) * F_OUT + 2 * lane) = o;
    o.x = wl2.x * a2.x * r2; o.y = wl2.y * a2.y * r2;
    *(float2*)(out + ((size_t)2 * N_NODES + n) * F_OUT + 2 * lane) = o;
    o.x = wl3.x * a3.x * r3; o.y = wl3.y * a3.y * r3;
    *(float2*)(out + ((size_t)3 * N_NODES + n) * F_OUT + 2 * lane) = o;
  }
}

extern "C" void kernel_launch(void* const* d_in, const int* in_sizes, int n_in,
                              void* d_out, int out_size, void* d_ws, size_t ws_size,
                              hipStream_t stream) {
  const float* x = (const float*)d_in[0];
  const float* w = (const float*)d_in[1];
  const float* a = (const float*)d_in[2];
  const int* ei = (const int*)d_in[3];
  const int* src = ei;
  const int* dst = ei + N_EDGES;
  float* out = (float*)d_out;

  char* p = (char*)d_ws;
  float4* s_src4 = (float4*)p;      p += (size_t)N_NODES * 16;
  float4* s_dst4 = (float4*)p;      p += (size_t)N_NODES * 16;
  int* gc = (int*)p;                p += 4096;                        // K1 counters
  unsigned int* region = (unsigned int*)p;
  p += (size_t)K1 * SCAP * 4;                                        // 6.8 MB

  hipMemsetAsync(gc, 0, 4096, stream);

  score_kernel<<<(N_NODES * 64 + 255) / 256, 256, 0, stream>>>(x, w, a, s_src4, s_dst4);
  partition_kernel<<<P1_BLOCKS, 256, 0, stream>>>(src, dst, gc, region);
  agg_kernel<<<GROUPS, 256, 0, stream>>>(x, w, s_src4, s_dst4, gc, region, out);
}

// Round 2
// 321.352 us; speedup vs baseline: 1.0774x; 1.0774x over previous
//
#include <hip/hip_runtime.h>

#define N_NODES 50000
#define N_EDGES 1600000
#define N_HEAD 4
#define F_OUT 128
#define CAP 96        // per-node bucket capacity; Poisson(32), P(>96) ~ 5e-14
#define NPS 512       // nodes per super-bucket
#define K1 98         // ceil(50000/512)
#define SCAP 17408    // super capacity: mean 16384 + 8 sigma(128)
#define NPG 32        // nodes per agg block
#define GROUPS 1563   // ceil(50000/32)
#define EPB 2048      // edges per partition block (was 4096; 782 blocks for occupancy)
#define P1_BLOCKS ((N_EDGES + EPB - 1) / EPB)   // 782

// ---------------- K1: per-node scores, packed float4 (h0..h3) per node ----------
__global__ void __launch_bounds__(256) score_kernel(
    const float* __restrict__ x, const float* __restrict__ w,
    const float* __restrict__ a, float4* __restrict__ s_src4,
    float4* __restrict__ s_dst4) {
  int wv = (blockIdx.x * blockDim.x + threadIdx.x) >> 6;
  int lane = threadIdx.x & 63;
  if (wv >= N_NODES) return;
  float xv0 = x[wv * F_OUT + lane];
  float xv1 = x[wv * F_OUT + 64 + lane];
  float ps[N_HEAD], pd[N_HEAD];
#pragma unroll
  for (int h = 0; h < N_HEAD; ++h) {
    float w0 = w[h * F_OUT + lane];
    float w1 = w[h * F_OUT + 64 + lane];
    float as0 = a[h * 2 * F_OUT + lane];
    float as1 = a[h * 2 * F_OUT + 64 + lane];
    float ad0 = a[h * 2 * F_OUT + F_OUT + lane];
    float ad1 = a[h * 2 * F_OUT + F_OUT + 64 + lane];
    ps[h] = xv0 * w0 * as0 + xv1 * w1 * as1;
    pd[h] = xv0 * w0 * ad0 + xv1 * w1 * ad1;
  }
#pragma unroll
  for (int off = 32; off > 0; off >>= 1) {
#pragma unroll
    for (int h = 0; h < N_HEAD; ++h) {
      ps[h] += __shfl_xor(ps[h], off, 64);
      pd[h] += __shfl_xor(pd[h], off, 64);
    }
  }
  if (lane == 0) {
    s_src4[wv] = make_float4(ps[0], ps[1], ps[2], ps[3]);
    s_dst4[wv] = make_float4(pd[0], pd[1], pd[2], pd[3]);
  }
}

// ---------------- K2: block-local counting sort -> coalesced run writes ---------
// Packs (src<<16)|dst (both < 65536). Coarse bucket = src>>9 (=packed>>25).
__global__ void __launch_bounds__(256) partition_kernel(
    const int* __restrict__ src, const int* __restrict__ dst,
    int* __restrict__ gc, unsigned int* __restrict__ region) {
  __shared__ int hist[K1], cur[K1], lstart[K1], gpos[K1];
  __shared__ unsigned int staging[EPB];
  const int tid = threadIdx.x;
  const int base = blockIdx.x * EPB;
  int vc = N_EDGES - base;
  if (vc > EPB) vc = EPB;

  unsigned int pk[EPB / 256];
#pragma unroll
  for (int k = 0; k < EPB / 256; ++k) {
    int i = k * 256 + tid;
    if (i < vc) {
      unsigned int s = (unsigned int)src[base + i];
      unsigned int d = (unsigned int)dst[base + i];
      pk[k] = (s << 16) | d;           // valid packed can never be 0xffffffff
    } else {
      pk[k] = 0xffffffffu;
    }
  }
  if (tid < K1) { hist[tid] = 0; cur[tid] = 0; }
  __syncthreads();
#pragma unroll
  for (int k = 0; k < EPB / 256; ++k)
    if (pk[k] != 0xffffffffu) atomicAdd(&hist[pk[k] >> 25], 1);
  __syncthreads();
  // wave 0: exclusive scan of hist + global reservation
  if (tid < 64) {
    int carry = 0;
    for (int b0 = 0; b0 < K1; b0 += 64) {
      int idx = b0 + tid;
      int h = (idx < K1) ? hist[idx] : 0;
      int v = h;
#pragma unroll
      for (int off = 1; off < 64; off <<= 1) {
        int t = __shfl_up(v, off, 64);
        if (tid >= off) v += t;
      }
      if (idx < K1) {
        lstart[idx] = carry + v - h;
        gpos[idx] = atomicAdd(&gc[idx], h);
      }
      carry += __shfl(v, 63, 64);
    }
  }
  __syncthreads();
  // place into LDS staging, sorted by coarse bucket
#pragma unroll
  for (int k = 0; k < EPB / 256; ++k) {
    if (pk[k] != 0xffffffffu) {
      int b = pk[k] >> 25;
      int pos = lstart[b] + atomicAdd(&cur[b], 1);
      staging[pos] = pk[k];
    }
  }
  __syncthreads();
  // copy out: consecutive lanes -> consecutive global addresses within each run
  for (int i = tid; i < vc; i += 256) {
    unsigned int v = staging[i];
    int b = v >> 25;
    int off = gpos[b] + (i - lstart[b]);
    if (off < SCAP) region[(size_t)b * SCAP + off] = v;
  }
}

// ---------------- K3: fused LDS-bucket + gather/accumulate ----------------------
// One block per 32-node group; scans its super region, LDS-buckets its edges,
// then wave-per-node phase A (weights) / phase B (paired x-gather + FMA).
// Phase B pairing: lanes 0-31 handle even edges, lanes 32-63 odd edges; each
// lane covers 4 features via float4 -> one dwordx4 instr gathers 2 rows (1KB).

#define EDGE_FMA(W, X)                                                     \
  acc0.x = fmaf(W.x, X.x, acc0.x); acc0.y = fmaf(W.x, X.y, acc0.y);        \
  acc0.z = fmaf(W.x, X.z, acc0.z); acc0.w = fmaf(W.x, X.w, acc0.w);        \
  acc1.x = fmaf(W.y, X.x, acc1.x); acc1.y = fmaf(W.y, X.y, acc1.y);        \
  acc1.z = fmaf(W.y, X.z, acc1.z); acc1.w = fmaf(W.y, X.w, acc1.w);        \
  acc2.x = fmaf(W.z, X.x, acc2.x); acc2.y = fmaf(W.z, X.y, acc2.y);        \
  acc2.z = fmaf(W.z, X.z, acc2.z); acc2.w = fmaf(W.z, X.w, acc2.w);        \
  acc3.x = fmaf(W.w, X.x, acc3.x); acc3.y = fmaf(W.w, X.y, acc3.y);        \
  acc3.z = fmaf(W.w, X.z, acc3.z); acc3.w = fmaf(W.w, X.w, acc3.w);

#define SCAN_PROC(v)                                                       \
  {                                                                        \
    unsigned int s_ = (v) >> 16;                                           \
    if ((s_ >> 5) == gtag) {                                               \
      int l_ = s_ & 31;                                                    \
      int p_ = atomicAdd(&ncnt[l_], 1);                                    \
      if (p_ < CAP) nbkt[l_][p_] = (int)((v) & 0xffffu);                   \
    }                                                                      \
  }

__global__ void __launch_bounds__(256, 6) agg_kernel(
    const float* __restrict__ x, const float* __restrict__ w,
    const float4* __restrict__ s_src4, const float4* __restrict__ s_dst4,
    const int* __restrict__ gc, const unsigned int* __restrict__ region,
    float* __restrict__ out) {
  __shared__ int ncnt[NPG];
  __shared__ int nbkt[NPG][CAP];
  __shared__ float4 lds_w[4][CAP];
  const int tid = threadIdx.x;
  const int g = blockIdx.x;
  const int sb = g >> 4;                 // 16 groups per super (512/32)
  int c = gc[sb];
  if (c > SCAP) c = SCAP;
  if (tid < NPG) ncnt[tid] = 0;
  __syncthreads();

  // ---- scan super region, 4 loads in flight per thread ----
  const unsigned int* reg = region + (size_t)sb * SCAP;
  const unsigned int gtag = (unsigned int)g;
  {
    int i = tid;
    for (; i + 768 < c; i += 1024) {
      unsigned int v0 = reg[i];
      unsigned int v1 = reg[i + 256];
      unsigned int v2 = reg[i + 512];
      unsigned int v3 = reg[i + 768];
      SCAN_PROC(v0); SCAN_PROC(v1); SCAN_PROC(v2); SCAN_PROC(v3);
    }
    for (; i < c; i += 256) { unsigned int v0 = reg[i]; SCAN_PROC(v0); }
  }
  __syncthreads();

  const int ws = tid >> 6, lane = tid & 63;
  const int half = lane >> 5;            // 0: even edges, 1: odd edges
  const int sl = lane & 31;              // feature group: feats 4*sl..4*sl+3
  const float4* x4 = (const float4*)x;   // 32 float4 per row

  for (int l = ws; l < NPG; l += 4) {
    int n = g * NPG + l;
    if (n >= N_NODES) break;
    int m = ncnt[l];
    m = (m < CAP) ? m : CAP;
    float4 ss = s_src4[n];

    // ---- Phase A: edge weights into wave-private LDS, per-lane partial sums ----
    float p0 = 0.f, p1 = 0.f, p2 = 0.f, p3 = 0.f;
    for (int j = lane; j < m; j += 64) {
      int d = nbkt[l][j];
      float4 sd = s_dst4[d];
      float sc0 = ss.x + sd.x, sc1 = ss.y + sd.y, sc2 = ss.z + sd.z, sc3 = ss.w + sd.w;
      float e0 = __expf(-fmaxf(sc0, 0.2f * sc0));
      float e1 = __expf(-fmaxf(sc1, 0.2f * sc1));
      float e2 = __expf(-fmaxf(sc2, 0.2f * sc2));
      float e3 = __expf(-fmaxf(sc3, 0.2f * sc3));
      lds_w[ws][j] = make_float4(e0, e1, e2, e3);
      p0 += e0; p1 += e1; p2 += e2; p3 += e3;
    }
    // pad bucket to multiple of 8 with zero-weight dummy edges (row 0)
    int m_pad = (m + 7) & ~7;            // <= CAP since CAP % 8 == 0
    if (lane < m_pad - m) {
      nbkt[l][m + lane] = 0;
      lds_w[ws][m + lane] = make_float4(0.f, 0.f, 0.f, 0.f);
    }

    // ---- Phase B: paired gather, 4 dwordx4 (8 edges, 4KB) in flight ----
    float4 acc0 = {0.f, 0.f, 0.f, 0.f}, acc1 = {0.f, 0.f, 0.f, 0.f};
    float4 acc2 = {0.f, 0.f, 0.f, 0.f}, acc3 = {0.f, 0.f, 0.f, 0.f};
    for (int t = 0; t < m_pad; t += 8) {
      int e0 = t + half, e1 = t + 2 + half, e2 = t + 4 + half, e3 = t + 6 + half;
      int d0 = nbkt[l][e0];
      int d1 = nbkt[l][e1];
      int d2 = nbkt[l][e2];
      int d3 = nbkt[l][e3];
      float4 x0 = x4[(size_t)d0 * 32 + sl];
      float4 x1 = x4[(size_t)d1 * 32 + sl];
      float4 x2 = x4[(size_t)d2 * 32 + sl];
      float4 x3 = x4[(size_t)d3 * 32 + sl];
      float4 w0 = lds_w[ws][e0];
      float4 w1 = lds_w[ws][e1];
      float4 w2 = lds_w[ws][e2];
      float4 w3 = lds_w[ws][e3];
      EDGE_FMA(w0, x0)
      EDGE_FMA(w1, x1)
      EDGE_FMA(w2, x2)
      EDGE_FMA(w3, x3)
    }

    // ---- cross-half reduction (even-edge + odd-edge partials) ----
    acc0.x += __shfl_xor(acc0.x, 32, 64); acc0.y += __shfl_xor(acc0.y, 32, 64);
    acc0.z += __shfl_xor(acc0.z, 32, 64); acc0.w += __shfl_xor(acc0.w, 32, 64);
    acc1.x += __shfl_xor(acc1.x, 32, 64); acc1.y += __shfl_xor(acc1.y, 32, 64);
    acc1.z += __shfl_xor(acc1.z, 32, 64); acc1.w += __shfl_xor(acc1.w, 32, 64);
    acc2.x += __shfl_xor(acc2.x, 32, 64); acc2.y += __shfl_xor(acc2.y, 32, 64);
    acc2.z += __shfl_xor(acc2.z, 32, 64); acc2.w += __shfl_xor(acc2.w, 32, 64);
    acc3.x += __shfl_xor(acc3.x, 32, 64); acc3.y += __shfl_xor(acc3.y, 32, 64);
    acc3.z += __shfl_xor(acc3.z, 32, 64); acc3.w += __shfl_xor(acc3.w, 32, 64);

    // ---- rowsum reduction (phase A partials live across all 64 lanes) ----
#pragma unroll
    for (int off = 32; off > 0; off >>= 1) {
      p0 += __shfl_xor(p0, off, 64);
      p1 += __shfl_xor(p1, off, 64);
      p2 += __shfl_xor(p2, off, 64);
      p3 += __shfl_xor(p3, off, 64);
    }
    float r0 = 1.f / p0, r1 = 1.f / p1, r2 = 1.f / p2, r3 = 1.f / p3;

    // ---- epilogue: lanes 0-31 write heads {0,2}, lanes 32-63 heads {1,3} ----
    const float4* w4 = (const float4*)w;
    float4 wA = w4[(half ? 1 : 0) * 32 + sl];
    float4 wB = w4[(half ? 3 : 2) * 32 + sl];
    float4 aA = half ? acc1 : acc0;
    float4 aB = half ? acc3 : acc2;
    float rA = half ? r1 : r0;
    float rB = half ? r3 : r2;
    float4 o;
    o.x = wA.x * aA.x * rA; o.y = wA.y * aA.y * rA;
    o.z = wA.z * aA.z * rA; o.w = wA.w * aA.w * rA;
    *(float4*)(out + ((size_t)half * N_NODES + n) * F_OUT + 4 * sl) = o;
    o.x = wB.x * aB.x * rB; o.y = wB.y * aB.y * rB;
    o.z = wB.z * aB.z * rB; o.w = wB.w * aB.w * rB;
    *(float4*)(out + ((size_t)(2 + half) * N_NODES + n) * F_OUT + 4 * sl) = o;
  }
}

extern "C" void kernel_launch(void* const* d_in, const int* in_sizes, int n_in,
                              void* d_out, int out_size, void* d_ws, size_t ws_size,
                              hipStream_t stream) {
  const float* x = (const float*)d_in[0];
  const float* w = (const float*)d_in[1];
  const float* a = (const float*)d_in[2];
  const int* ei = (const int*)d_in[3];
  const int* src = ei;
  const int* dst = ei + N_EDGES;
  float* out = (float*)d_out;

  char* p = (char*)d_ws;
  float4* s_src4 = (float4*)p;      p += (size_t)N_NODES * 16;
  float4* s_dst4 = (float4*)p;      p += (size_t)N_NODES * 16;
  int* gc = (int*)p;                p += 4096;                        // K1 counters
  unsigned int* region = (unsigned int*)p;
  p += (size_t)K1 * SCAP * 4;                                        // 6.8 MB

  hipMemsetAsync(gc, 0, 4096, stream);

  score_kernel<<<(N_NODES * 64 + 255) / 256, 256, 0, stream>>>(x, w, a, s_src4, s_dst4);
  partition_kernel<<<P1_BLOCKS, 256, 0, stream>>>(src, dst, gc, region);
  agg_kernel<<<GROUPS, 256, 0, stream>>>(x, w, s_src4, s_dst4, gc, region, out);
}

// Round 3
// 310.473 us; speedup vs baseline: 1.1151x; 1.0350x over previous
//
#include <hip/hip_runtime.h>

#define N_NODES 50000
#define N_EDGES 1600000
#define N_HEAD 4
#define F_OUT 128
#define CAP 96        // per-node bucket capacity; Poisson(32), P(>96) ~ 5e-14
#define NPS 512       // nodes per super-bucket
#define K1 98         // ceil(50000/512)
#define SCAP 17408    // super capacity: mean 16384 + 8 sigma(128)
#define NPG 64        // nodes per agg block (8 waves, one node per wave per pass)
#define GROUPS 782    // ceil(50000/64)
#define EPB 2048      // edges per partition block
#define P1_BLOCKS ((N_EDGES + EPB - 1) / EPB)   // 782
#define SCORE_BLOCKS ((N_NODES * 64 + 255) / 256)  // 12500
#define FUSED_BLOCKS (P1_BLOCKS + SCORE_BLOCKS)

// ---------------- fused K1+K2: partition blocks first (long pole), score fills in
__global__ void __launch_bounds__(256) prep_kernel(
    const float* __restrict__ x, const float* __restrict__ w,
    const float* __restrict__ a, float4* __restrict__ s_src4,
    float4* __restrict__ s_dst4,
    const int* __restrict__ src, const int* __restrict__ dst,
    int* __restrict__ gc, unsigned int* __restrict__ region) {
  __shared__ int hist[K1], cur[K1], lstart[K1], gpos[K1];
  __shared__ unsigned int staging[EPB];
  const int tid = threadIdx.x;

  if (blockIdx.x >= P1_BLOCKS) {
    // ---------------- score part ----------------
    int bid = blockIdx.x - P1_BLOCKS;
    int wv = (bid * 256 + tid) >> 6;
    int lane = tid & 63;
    if (wv >= N_NODES) return;
    float xv0 = x[wv * F_OUT + lane];
    float xv1 = x[wv * F_OUT + 64 + lane];
    float ps[N_HEAD], pd[N_HEAD];
#pragma unroll
    for (int h = 0; h < N_HEAD; ++h) {
      float w0 = w[h * F_OUT + lane];
      float w1 = w[h * F_OUT + 64 + lane];
      float as0 = a[h * 2 * F_OUT + lane];
      float as1 = a[h * 2 * F_OUT + 64 + lane];
      float ad0 = a[h * 2 * F_OUT + F_OUT + lane];
      float ad1 = a[h * 2 * F_OUT + F_OUT + 64 + lane];
      ps[h] = xv0 * w0 * as0 + xv1 * w1 * as1;
      pd[h] = xv0 * w0 * ad0 + xv1 * w1 * ad1;
    }
#pragma unroll
    for (int off = 32; off > 0; off >>= 1) {
#pragma unroll
      for (int h = 0; h < N_HEAD; ++h) {
        ps[h] += __shfl_xor(ps[h], off, 64);
        pd[h] += __shfl_xor(pd[h], off, 64);
      }
    }
    if (lane == 0) {
      s_src4[wv] = make_float4(ps[0], ps[1], ps[2], ps[3]);
      s_dst4[wv] = make_float4(pd[0], pd[1], pd[2], pd[3]);
    }
    return;
  }

  // ---------------- partition part ----------------
  const int base = blockIdx.x * EPB;
  int vc = N_EDGES - base;
  if (vc > EPB) vc = EPB;

  unsigned int pk[EPB / 256];
#pragma unroll
  for (int k = 0; k < EPB / 256; ++k) {
    int i = k * 256 + tid;
    if (i < vc) {
      unsigned int s = (unsigned int)src[base + i];
      unsigned int d = (unsigned int)dst[base + i];
      pk[k] = (s << 16) | d;           // valid packed can never be 0xffffffff
    } else {
      pk[k] = 0xffffffffu;
    }
  }
  if (tid < K1) { hist[tid] = 0; cur[tid] = 0; }
  __syncthreads();
#pragma unroll
  for (int k = 0; k < EPB / 256; ++k)
    if (pk[k] != 0xffffffffu) atomicAdd(&hist[pk[k] >> 25], 1);
  __syncthreads();
  // wave 0: exclusive scan of hist + global reservation
  if (tid < 64) {
    int carry = 0;
    for (int b0 = 0; b0 < K1; b0 += 64) {
      int idx = b0 + tid;
      int h = (idx < K1) ? hist[idx] : 0;
      int v = h;
#pragma unroll
      for (int off = 1; off < 64; off <<= 1) {
        int t = __shfl_up(v, off, 64);
        if (tid >= off) v += t;
      }
      if (idx < K1) {
        lstart[idx] = carry + v - h;
        gpos[idx] = atomicAdd(&gc[idx], h);
      }
      carry += __shfl(v, 63, 64);
    }
  }
  __syncthreads();
  // place into LDS staging, sorted by coarse bucket
#pragma unroll
  for (int k = 0; k < EPB / 256; ++k) {
    if (pk[k] != 0xffffffffu) {
      int b = pk[k] >> 25;
      int pos = lstart[b] + atomicAdd(&cur[b], 1);
      staging[pos] = pk[k];
    }
  }
  __syncthreads();
  // copy out: consecutive lanes -> consecutive global addresses within each run
  for (int i = tid; i < vc; i += 256) {
    unsigned int v = staging[i];
    int b = v >> 25;
    int off = gpos[b] + (i - lstart[b]);
    if (off < SCAP) region[(size_t)b * SCAP + off] = v;
  }
}

// ---------------- K3: fused LDS-bucket + gather/accumulate ----------------------
// One 512-thread block per 64-node group (8 groups per super): scans its super
// region once, LDS-buckets its edges, then wave-per-node phase A (weights) /
// phase B (paired x-gather + FMA). Grid 782 -> 3 blocks/CU -> 24 waves/CU.

#define EDGE_FMA(W, X)                                                     \
  acc0.x = fmaf(W.x, X.x, acc0.x); acc0.y = fmaf(W.x, X.y, acc0.y);        \
  acc0.z = fmaf(W.x, X.z, acc0.z); acc0.w = fmaf(W.x, X.w, acc0.w);        \
  acc1.x = fmaf(W.y, X.x, acc1.x); acc1.y = fmaf(W.y, X.y, acc1.y);        \
  acc1.z = fmaf(W.y, X.z, acc1.z); acc1.w = fmaf(W.y, X.w, acc1.w);        \
  acc2.x = fmaf(W.z, X.x, acc2.x); acc2.y = fmaf(W.z, X.y, acc2.y);        \
  acc2.z = fmaf(W.z, X.z, acc2.z); acc2.w = fmaf(W.z, X.w, acc2.w);        \
  acc3.x = fmaf(W.w, X.x, acc3.x); acc3.y = fmaf(W.w, X.y, acc3.y);        \
  acc3.z = fmaf(W.w, X.z, acc3.z); acc3.w = fmaf(W.w, X.w, acc3.w);

#define SCAN_PROC(v)                                                       \
  {                                                                        \
    unsigned int s_ = (v) >> 16;                                           \
    if ((s_ >> 6) == gtag) {                                               \
      int l_ = s_ & 63;                                                    \
      int p_ = atomicAdd(&ncnt[l_], 1);                                    \
      if (p_ < CAP) nbkt[l_][p_] = (int)((v) & 0xffffu);                   \
    }                                                                      \
  }

__global__ void __launch_bounds__(512, 6) agg_kernel(
    const float* __restrict__ x, const float* __restrict__ w,
    const float4* __restrict__ s_src4, const float4* __restrict__ s_dst4,
    const int* __restrict__ gc, const unsigned int* __restrict__ region,
    float* __restrict__ out) {
  __shared__ int ncnt[NPG];
  __shared__ int nbkt[NPG][CAP];        // 24.6 KB
  __shared__ float4 lds_w[8][CAP];      // 12.3 KB
  const int tid = threadIdx.x;
  const int g = blockIdx.x;
  const int sb = g >> 3;                 // 8 groups per super (512/64)
  int c = gc[sb];
  if (c > SCAP) c = SCAP;
  if (tid < NPG) ncnt[tid] = 0;
  __syncthreads();

  // ---- scan super region once per block, 4 loads in flight per thread ----
  const unsigned int* reg = region + (size_t)sb * SCAP;
  const unsigned int gtag = (unsigned int)g;
  {
    int i = tid;
    for (; i + 1536 < c; i += 2048) {
      unsigned int v0 = reg[i];
      unsigned int v1 = reg[i + 512];
      unsigned int v2 = reg[i + 1024];
      unsigned int v3 = reg[i + 1536];
      SCAN_PROC(v0); SCAN_PROC(v1); SCAN_PROC(v2); SCAN_PROC(v3);
    }
    for (; i < c; i += 512) { unsigned int v0 = reg[i]; SCAN_PROC(v0); }
  }
  __syncthreads();

  const int ws = tid >> 6, lane = tid & 63;
  const int half = lane >> 5;            // 0: even edges, 1: odd edges
  const int sl = lane & 31;              // feature group: feats 4*sl..4*sl+3
  const float4* x4 = (const float4*)x;   // 32 float4 per row

  for (int l = ws; l < NPG; l += 8) {
    int n = g * NPG + l;
    if (n >= N_NODES) break;
    int m = ncnt[l];
    m = (m < CAP) ? m : CAP;
    float4 ss = s_src4[n];

    // ---- Phase A: edge weights into wave-private LDS, per-lane partial sums ----
    float p0 = 0.f, p1 = 0.f, p2 = 0.f, p3 = 0.f;
    for (int j = lane; j < m; j += 64) {
      int d = nbkt[l][j];
      float4 sd = s_dst4[d];
      float sc0 = ss.x + sd.x, sc1 = ss.y + sd.y, sc2 = ss.z + sd.z, sc3 = ss.w + sd.w;
      float e0 = __expf(-fmaxf(sc0, 0.2f * sc0));
      float e1 = __expf(-fmaxf(sc1, 0.2f * sc1));
      float e2 = __expf(-fmaxf(sc2, 0.2f * sc2));
      float e3 = __expf(-fmaxf(sc3, 0.2f * sc3));
      lds_w[ws][j] = make_float4(e0, e1, e2, e3);
      p0 += e0; p1 += e1; p2 += e2; p3 += e3;
    }
    // pad bucket to multiple of 8 with zero-weight dummy edges (row 0)
    int m_pad = (m + 7) & ~7;            // <= CAP since CAP % 8 == 0
    if (lane < m_pad - m) {
      nbkt[l][m + lane] = 0;
      lds_w[ws][m + lane] = make_float4(0.f, 0.f, 0.f, 0.f);
    }

    // ---- Phase B: paired gather, 4 dwordx4 (8 edges, 4KB) in flight ----
    float4 acc0 = {0.f, 0.f, 0.f, 0.f}, acc1 = {0.f, 0.f, 0.f, 0.f};
    float4 acc2 = {0.f, 0.f, 0.f, 0.f}, acc3 = {0.f, 0.f, 0.f, 0.f};
    for (int t = 0; t < m_pad; t += 8) {
      int e0 = t + half, e1 = t + 2 + half, e2 = t + 4 + half, e3 = t + 6 + half;
      int d0 = nbkt[l][e0];
      int d1 = nbkt[l][e1];
      int d2 = nbkt[l][e2];
      int d3 = nbkt[l][e3];
      float4 x0 = x4[(size_t)d0 * 32 + sl];
      float4 x1 = x4[(size_t)d1 * 32 + sl];
      float4 x2 = x4[(size_t)d2 * 32 + sl];
      float4 x3 = x4[(size_t)d3 * 32 + sl];
      float4 w0 = lds_w[ws][e0];
      float4 w1 = lds_w[ws][e1];
      float4 w2 = lds_w[ws][e2];
      float4 w3 = lds_w[ws][e3];
      EDGE_FMA(w0, x0)
      EDGE_FMA(w1, x1)
      EDGE_FMA(w2, x2)
      EDGE_FMA(w3, x3)
    }

    // ---- cross-half reduction (even-edge + odd-edge partials) ----
    acc0.x += __shfl_xor(acc0.x, 32, 64); acc0.y += __shfl_xor(acc0.y, 32, 64);
    acc0.z += __shfl_xor(acc0.z, 32, 64); acc0.w += __shfl_xor(acc0.w, 32, 64);
    acc1.x += __shfl_xor(acc1.x, 32, 64); acc1.y += __shfl_xor(acc1.y, 32, 64);
    acc1.z += __shfl_xor(acc1.z, 32, 64); acc1.w += __shfl_xor(acc1.w, 32, 64);
    acc2.x += __shfl_xor(acc2.x, 32, 64); acc2.y += __shfl_xor(acc2.y, 32, 64);
    acc2.z += __shfl_xor(acc2.z, 32, 64); acc2.w += __shfl_xor(acc2.w, 32, 64);
    acc3.x += __shfl_xor(acc3.x, 32, 64); acc3.y += __shfl_xor(acc3.y, 32, 64);
    acc3.z += __shfl_xor(acc3.z, 32, 64); acc3.w += __shfl_xor(acc3.w, 32, 64);

    // ---- rowsum reduction (phase A partials live across all 64 lanes) ----
#pragma unroll
    for (int off = 32; off > 0; off >>= 1) {
      p0 += __shfl_xor(p0, off, 64);
      p1 += __shfl_xor(p1, off, 64);
      p2 += __shfl_xor(p2, off, 64);
      p3 += __shfl_xor(p3, off, 64);
    }
    float r0 = 1.f / p0, r1 = 1.f / p1, r2 = 1.f / p2, r3 = 1.f / p3;

    // ---- epilogue: lanes 0-31 write heads {0,2}, lanes 32-63 heads {1,3} ----
    const float4* w4 = (const float4*)w;
    float4 wA = w4[(half ? 1 : 0) * 32 + sl];
    float4 wB = w4[(half ? 3 : 2) * 32 + sl];
    float4 aA = half ? acc1 : acc0;
    float4 aB = half ? acc3 : acc2;
    float rA = half ? r1 : r0;
    float rB = half ? r3 : r2;
    float4 o;
    o.x = wA.x * aA.x * rA; o.y = wA.y * aA.y * rA;
    o.z = wA.z * aA.z * rA; o.w = wA.w * aA.w * rA;
    *(float4*)(out + ((size_t)half * N_NODES + n) * F_OUT + 4 * sl) = o;
    o.x = wB.x * aB.x * rB; o.y = wB.y * aB.y * rB;
    o.z = wB.z * aB.z * rB; o.w = wB.w * aB.w * rB;
    *(float4*)(out + ((size_t)(2 + half) * N_NODES + n) * F_OUT + 4 * sl) = o;
  }
}

extern "C" void kernel_launch(void* const* d_in, const int* in_sizes, int n_in,
                              void* d_out, int out_size, void* d_ws, size_t ws_size,
                              hipStream_t stream) {
  const float* x = (const float*)d_in[0];
  const float* w = (const float*)d_in[1];
  const float* a = (const float*)d_in[2];
  const int* ei = (const int*)d_in[3];
  const int* src = ei;
  const int* dst = ei + N_EDGES;
  float* out = (float*)d_out;

  char* p = (char*)d_ws;
  float4* s_src4 = (float4*)p;      p += (size_t)N_NODES * 16;
  float4* s_dst4 = (float4*)p;      p += (size_t)N_NODES * 16;
  int* gc = (int*)p;                p += 4096;                        // K1 counters
  unsigned int* region = (unsigned int*)p;
  p += (size_t)K1 * SCAP * 4;                                        // 6.8 MB

  hipMemsetAsync(gc, 0, 4096, stream);

  prep_kernel<<<FUSED_BLOCKS, 256, 0, stream>>>(x, w, a, s_src4, s_dst4,
                                                src, dst, gc, region);
  agg_kernel<<<GROUPS, 512, 0, stream>>>(x, w, s_src4, s_dst4, gc, region, out);
}